// Round 5
// baseline (1497.686 us; speedup 1.0000x reference)
//
#include <hip/hip_runtime.h>
#include <cstdint>
#include <cstddef>

#define B64 64
#define TDEC 20
#define VV 12000
#define EE 256
#define HH 512
#define DD 1024
#define RR 36

typedef __attribute__((ext_vector_type(8))) short bf16x8;
typedef __attribute__((ext_vector_type(4))) float f32x4;

__device__ __forceinline__ unsigned short f2b(float f) {
    unsigned u = __float_as_uint(f);
    unsigned r = (u + 0x7FFFu + ((u >> 16) & 1u)) >> 16;
    return (unsigned short)r;
}
__device__ __forceinline__ float b2f(unsigned short h) {
    return __uint_as_float(((unsigned)h) << 16);
}

// ---------------- sort (stable argsort desc by length) ----------------
__global__ void k_sort(const int* __restrict__ cap_len,
                       const int* __restrict__ captions,
                       int* __restrict__ sind, int* __restrict__ dec_i,
                       int* __restrict__ caps_s,
                       float* __restrict__ out_dec,
                       float* __restrict__ out_sind,
                       float* __restrict__ out_caps)
{
    int i = threadIdx.x;
    __shared__ int lens[B64];
    lens[i] = cap_len[i];
    __syncthreads();
    int li = lens[i];
    int rank = 0;
    for (int j = 0; j < B64; ++j) {
        int lj = lens[j];
        if (lj > li || (lj == li && j < i)) rank++;
    }
    sind[rank] = i;
    dec_i[rank] = li - 1;
    out_dec[rank] = (float)(li - 1);
    out_sind[rank] = (float)i;
    for (int t = 0; t < 21; ++t) {
        int tok = captions[i * 21 + t];
        caps_s[rank * 21 + t] = tok;
        if (t >= 1) out_caps[rank * 20 + (t - 1)] = (float)tok;
    }
}

// ---------------- init: hbuf0 (packed h0), cT, ra=0, cnt=0 ----------------
__global__ void k_init(const float* __restrict__ h0, const int* __restrict__ sind,
                       unsigned* __restrict__ hbuf0, float* __restrict__ cT,
                       float* __restrict__ ra_g, unsigned* __restrict__ cnt)
{
    int idx = blockIdx.x * blockDim.x + threadIdx.x;
    if (idx == 0) *cnt = 0u;
    if (idx < B64 * RR) ra_g[idx] = 0.0f;
    if (idx < B64 * 256) {
        int b = idx >> 8, p = idx & 255;
        int sb = sind[b];
        float v0 = h0[sb * HH + 2 * p];
        float v1 = h0[sb * HH + 2 * p + 1];
        hbuf0[idx] = (unsigned)f2b(v0) | ((unsigned)f2b(v1) << 16);
    }
    if (idx < HH * B64) {
        int hp = idx >> 6, b = idx & 63;
        cT[idx] = h0[sind[b] * HH + hp];
    }
}

// ---------------- gather sorted object proposals -> bf16 ----------------
__global__ void k_gobjs(const float* __restrict__ objs, const int* __restrict__ sind,
                        unsigned short* __restrict__ objs_b)
{
    int idx = blockIdx.x * blockDim.x + threadIdx.x;
    if (idx >= B64 * RR * DD) return;
    int b = idx / (RR * DD);
    int rest = idx - b * (RR * DD);
    objs_b[idx] = f2b(objs[(size_t)sind[b] * (RR * DD) + rest]);
}

// ---------------- gather embeddings for all (t,b) -> bf16 ----------------
__global__ void k_gA(const float* __restrict__ embW, const int* __restrict__ caps_s,
                     unsigned short* __restrict__ AembB)
{
    int idx = blockIdx.x * blockDim.x + threadIdx.x;
    if (idx >= TDEC * B64 * EE) return;
    int tb = idx >> 8, e = idx & 255;
    int t = tb >> 6, b = tb & 63;
    int tok = caps_s[b * 21 + t];
    AembB[idx] = f2b(embW[(size_t)tok * EE + e]);
}

// ---------------- all weight conversions fused (grid-stride) ----------------
#define T_EMB  3072000
#define T_WIH  524288
#define T_RH   524288
#define T_WHB  131072
#define T_WC   3145728
#define T_ALL  (T_EMB + T_WIH + T_RH + T_WHB + T_WC)
__global__ void k_prep(const float* __restrict__ embW, const float* __restrict__ Wih,
                       const float* __restrict__ Whh, const float* __restrict__ rhW,
                       const float* __restrict__ whW,
                       unsigned short* __restrict__ embB, unsigned short* __restrict__ WihB,
                       unsigned short* __restrict__ rhW_b, unsigned short* __restrict__ whB,
                       unsigned short* __restrict__ Wc)
{
    for (int idx = blockIdx.x * blockDim.x + threadIdx.x; idx < T_ALL;
         idx += gridDim.x * blockDim.x) {
        int i = idx;
        if (i < T_EMB) { embB[i] = f2b(embW[i]); continue; }
        i -= T_EMB;
        if (i < T_WIH) {
            int row = i >> 8, col = i & 255;
            WihB[i] = f2b(Wih[(size_t)row * 1280 + col]);
            continue;
        }
        i -= T_WIH;
        if (i < T_RH) { rhW_b[i] = f2b(rhW[i]); continue; }
        i -= T_RH;
        if (i < T_WHB) { whB[i] = f2b(whW[i]); continue; }
        i -= T_WHB;
        int m = i / 1536, k = i - m * 1536;
        int hp = m >> 2, g = m & 3;
        int ro = g * 512 + hp;
        float v = (k < 1024) ? Wih[(size_t)ro * 1280 + 256 + k]
                             : Whh[(size_t)ro * 512 + (k - 1024)];
        Wc[i] = f2b(v);
    }
}

// ---------------- emb_sum partials + reduce (fp32 exact) ----------------
__global__ void k_embsum(const float* __restrict__ embW, float* __restrict__ partial)
{
    int e = threadIdx.x;
    int v0 = blockIdx.x * 50;
    float a = 0.0f;
    for (int v = v0; v < v0 + 50; ++v) a += embW[(size_t)v * EE + e];
    partial[blockIdx.x * EE + e] = a;
}
__global__ void k_embred(const float* __restrict__ partial, float* __restrict__ emb_sum)
{
    int e = threadIdx.x;
    float a = 0.0f;
    for (int j = 0; j < 240; ++j) a += partial[j * EE + e];
    emb_sum[e] = a;
}

// ---------------- pw[d] = emb_sum . wr_W[d,:] + V*wr_b[d] ----------------
__global__ void k_pwsum(const float* __restrict__ emb_sum, const float* __restrict__ wrW,
                        const float* __restrict__ wr_b, float* __restrict__ pw)
{
    __shared__ float es[EE];
    es[threadIdx.x] = emb_sum[threadIdx.x];
    __syncthreads();
    int d = blockIdx.x * 256 + threadIdx.x;
    float a = 0.0f;
    const float* row = wrW + (size_t)d * EE;
    for (int e = 0; e < EE; ++e) a = fmaf(es[e], row[e], a);
    pw[d] = a + 12000.0f * wr_b[d];
}

// ---------------- per-b: obj_sum -> s_wr, srb, sumv_wr, r_lin ----------
__global__ void k_objpre(const unsigned short* __restrict__ objs_b, const float* __restrict__ wrW,
                         const float* __restrict__ wr_b, const float* __restrict__ pw,
                         const float* __restrict__ rW, const float* __restrict__ r_b,
                         float* __restrict__ s_wr, float* __restrict__ srb,
                         float* __restrict__ sumv, float* __restrict__ r_lin)
{
    int b = blockIdx.x, tid = threadIdx.x;
    __shared__ float os[DD];
    __shared__ float red[256];
    const unsigned short* ob = objs_b + (size_t)b * RR * DD;
    for (int d = tid; d < DD; d += 256) {
        float a = 0.0f;
        for (int r = 0; r < RR; ++r) a += b2f(ob[r * DD + d]);
        os[d] = a;
    }
    __syncthreads();
    float a = 0.0f;
    for (int d = 0; d < DD; ++d) a = fmaf(os[d], wrW[(size_t)d * EE + tid], a);
    s_wr[b * EE + tid] = a;
    float p = 0.0f;
    for (int d = tid; d < DD; d += 256) p = fmaf(os[d], wr_b[d], p);
    red[tid] = p;
    __syncthreads();
    for (int s = 128; s > 0; s >>= 1) { if (tid < s) red[tid] += red[tid + s]; __syncthreads(); }
    if (tid == 0) srb[b] = red[0];
    if (tid < RR) {
        const unsigned short* row = ob + (size_t)tid * DD;
        float sv = 0.0f, rl = 0.0f;
        for (int d = 0; d < DD; ++d) { float x = b2f(row[d]); sv = fmaf(pw[d], x, sv); rl = fmaf(rW[d], x, rl); }
        sumv[b * RR + tid] = sv;
        r_lin[b * RR + tid] = rl + r_b[0];
    }
}

// ---------------- bf16 MFMA GEMM, fp32 out: C = A*B^T + bias1 + bias2 -------
__global__ __launch_bounds__(256) void k_bgemm(
    const unsigned short* __restrict__ A, int lda,
    const unsigned short* __restrict__ B, int ldb,
    float* __restrict__ C, int ldc, int K,
    const float* __restrict__ bias1, const float* __restrict__ bias2)
{
    int tid = threadIdx.x;
    int wv = tid >> 6, lane = tid & 63;
    int l15 = lane & 15, lg = lane >> 4;
    int m0 = blockIdx.x * 32 + (wv & 1) * 16;
    int n0 = blockIdx.y * 32 + (wv >> 1) * 16;
    const unsigned short* Ar = A + (size_t)(m0 + l15) * lda + lg * 8;
    const unsigned short* Br = B + (size_t)(n0 + l15) * ldb + lg * 8;
    f32x4 acc0 = {0.f, 0.f, 0.f, 0.f}, acc1 = {0.f, 0.f, 0.f, 0.f};
#pragma unroll 4
    for (int k0 = 0; k0 < K; k0 += 64) {
        bf16x8 a0 = *(const bf16x8*)(Ar + k0);
        bf16x8 b0 = *(const bf16x8*)(Br + k0);
        bf16x8 a1 = *(const bf16x8*)(Ar + k0 + 32);
        bf16x8 b1 = *(const bf16x8*)(Br + k0 + 32);
        acc0 = __builtin_amdgcn_mfma_f32_16x16x32_bf16(a0, b0, acc0, 0, 0, 0);
        acc1 = __builtin_amdgcn_mfma_f32_16x16x32_bf16(a1, b1, acc1, 0, 0, 0);
    }
    int n = n0 + l15;
    float badd = 0.0f;
    if (bias1) badd += bias1[n];
    if (bias2) badd += bias2[n];
#pragma unroll
    for (int r = 0; r < 4; ++r) {
        int m = m0 + 4 * lg + r;
        C[(size_t)m * ldc + n] = acc0[r] + acc1[r] + badd;
    }
}

// ---------------- bf16 MFMA GEMM, bf16 out row-major (rh_b16) ---------------
__global__ __launch_bounds__(256) void k_bgemm16(
    const unsigned short* __restrict__ A, int lda,
    const unsigned short* __restrict__ B, int ldb,
    unsigned short* __restrict__ C, int ldc, int K,
    const float* __restrict__ bias1)
{
    int tid = threadIdx.x;
    int wv = tid >> 6, lane = tid & 63;
    int l15 = lane & 15, lg = lane >> 4;
    int m0 = blockIdx.x * 32 + (wv & 1) * 16;
    int n0 = blockIdx.y * 32 + (wv >> 1) * 16;
    const unsigned short* Ar = A + (size_t)(m0 + l15) * lda + lg * 8;
    const unsigned short* Br = B + (size_t)(n0 + l15) * ldb + lg * 8;
    f32x4 acc0 = {0.f, 0.f, 0.f, 0.f}, acc1 = {0.f, 0.f, 0.f, 0.f};
#pragma unroll 4
    for (int k0 = 0; k0 < K; k0 += 64) {
        bf16x8 a0 = *(const bf16x8*)(Ar + k0);
        bf16x8 b0 = *(const bf16x8*)(Br + k0);
        bf16x8 a1 = *(const bf16x8*)(Ar + k0 + 32);
        bf16x8 b1 = *(const bf16x8*)(Br + k0 + 32);
        acc0 = __builtin_amdgcn_mfma_f32_16x16x32_bf16(a0, b0, acc0, 0, 0, 0);
        acc1 = __builtin_amdgcn_mfma_f32_16x16x32_bf16(a1, b1, acc1, 0, 0, 0);
    }
    int n = n0 + l15;
    float badd = bias1 ? bias1[n] : 0.0f;
#pragma unroll
    for (int r = 0; r < 4; ++r) {
        int m = m0 + 4 * lg + r;
        C[(size_t)m * ldc + n] = f2b(acc0[r] + acc1[r] + badd);
    }
}

// ---------------- OP2 GEMM: objs_b @ Wc[:, :1024]^T -> OP2[b][m][r] bf16 ----
__global__ __launch_bounds__(256) void k_opgemm(
    const unsigned short* __restrict__ A,      // objs_b [2304][1024]
    const unsigned short* __restrict__ Wc,     // [2048][1536], use cols 0..1024
    unsigned short* __restrict__ OP2)          // [64][2048][36]
{
    int tid = threadIdx.x;
    int wv = tid >> 6, lane = tid & 63;
    int l15 = lane & 15, lg = lane >> 4;
    int m0 = blockIdx.x * 32 + (wv & 1) * 16;
    int n0 = blockIdx.y * 32 + (wv >> 1) * 16;
    const unsigned short* Ar = A + (size_t)(m0 + l15) * 1024 + lg * 8;
    const unsigned short* Br = Wc + (size_t)(n0 + l15) * 1536 + lg * 8;
    f32x4 acc0 = {0.f, 0.f, 0.f, 0.f}, acc1 = {0.f, 0.f, 0.f, 0.f};
#pragma unroll 4
    for (int k0 = 0; k0 < 1024; k0 += 64) {
        bf16x8 a0 = *(const bf16x8*)(Ar + k0);
        bf16x8 b0 = *(const bf16x8*)(Br + k0);
        bf16x8 a1 = *(const bf16x8*)(Ar + k0 + 32);
        bf16x8 b1 = *(const bf16x8*)(Br + k0 + 32);
        acc0 = __builtin_amdgcn_mfma_f32_16x16x32_bf16(a0, b0, acc0, 0, 0, 0);
        acc1 = __builtin_amdgcn_mfma_f32_16x16x32_bf16(a1, b1, acc1, 0, 0, 0);
    }
    int n = n0 + l15;
#pragma unroll
    for (int r = 0; r < 4; ++r) {
        int m = m0 + 4 * lg + r;              // row of objs (b*36 + rr)
        int b = m / 36, rr = m - b * 36;
        OP2[((size_t)b * 2048 + n) * 36 + rr] = f2b(acc0[r] + acc1[r]);
    }
}

// ---------------- lightweight global barrier (relaxed agent atomics) --------
__device__ __forceinline__ void gbar(unsigned* cnt, unsigned round)
{
    __syncthreads();   // drains vmcnt: prior agent stores have reached coherence point
    if (threadIdx.x == 0) {
        __hip_atomic_fetch_add(cnt, 1u, __ATOMIC_RELAXED, __HIP_MEMORY_SCOPE_AGENT);
        while (__hip_atomic_load(cnt, __ATOMIC_RELAXED, __HIP_MEMORY_SCOPE_AGENT) < 64u * round) {
            __builtin_amdgcn_s_sleep(2);
        }
    }
    __syncthreads();
}

// ---------------- persistent fused recurrence, 64 blocks x 512 --------------
__global__ __launch_bounds__(512) void k_recur(
    const unsigned short* __restrict__ Wc,       // [2048][1536], cols 1024.. = Whh
    const unsigned short* __restrict__ OP2,      // [64][2048][36]
    const float* __restrict__ ge,                // [1280][2048]
    float* __restrict__ cT,                      // [512][64]
    const int* __restrict__ dec_i,
    const unsigned short* __restrict__ rh_b16,   // [64*36][512]
    const float* __restrict__ sumv, const float* __restrict__ r_lin,
    const unsigned short* __restrict__ whB,      // [512][256] (native whW)
    const float* __restrict__ wh_b, const float* __restrict__ wW, const float* __restrict__ w_b,
    const float* __restrict__ emb_sum,
    const float* __restrict__ s_wr, const float* __restrict__ srb,
    unsigned* __restrict__ hbuf0, unsigned* __restrict__ hbuf1,
    float* __restrict__ ra_g, unsigned* __restrict__ cnt,
    unsigned short* __restrict__ Gb, float* __restrict__ g0,
    float* __restrict__ attn_out)
{
    const int tid = threadIdx.x;
    const int blk = blockIdx.x;
    const int wv = tid >> 6, lane = tid & 63;
    const int l15 = lane & 15, lg = lane >> 4;
    // phase-1 geometry: 4 b-groups x 16 m-chunks
    const int bg = blk >> 4;
    const int mc = blk & 15;
    const int b1 = bg * 16 + l15;
    const int dec1 = dec_i[b1];
    const int m0 = mc * 128 + wv * 16;
    const int hpb = (m0 >> 2) + lg;
    // phase-2 geometry
    const int b2 = blk;
    const int dec2 = dec_i[b2];

    __shared__ unsigned short hb[16][520];
    __shared__ float ras[16][36];
    __shared__ float hs[512];
    __shared__ float up[256][2];
    __shared__ float rpart[RR][8];
    __shared__ float rvec_s[RR], ra_s[RR];
    __shared__ float red1[256], red2[256];

    for (int t = 0; t < TDEC; ++t) {
        unsigned* hsrc = (t & 1) ? hbuf1 : hbuf0;
        unsigned* hdst = (t & 1) ? hbuf0 : hbuf1;

        // ================= phase 1: gates (Whh MFMA + OP-sum) ================
        {
#pragma unroll
            for (int j = 0; j < 8; ++j) {
                int idx = j * 512 + tid;            // 0..4095
                int bi = idx >> 8, p = idx & 255;
                unsigned u = __hip_atomic_load(&hsrc[(bg * 16 + bi) * 256 + p],
                                               __ATOMIC_RELAXED, __HIP_MEMORY_SCOPE_AGENT);
                hb[bi][2 * p] = (unsigned short)(u & 0xFFFFu);
                hb[bi][2 * p + 1] = (unsigned short)(u >> 16);
            }
            for (int j = tid; j < 16 * RR; j += 512) {
                int bi = j / RR, r = j - bi * RR;
                ras[bi][r] = __hip_atomic_load(&ra_g[(bg * 16 + bi) * RR + r],
                                               __ATOMIC_RELAXED, __HIP_MEMORY_SCOPE_AGENT);
            }
            __syncthreads();
            const unsigned short* Ar = Wc + (size_t)(m0 + l15) * 1536 + 1024 + lg * 8;
            f32x4 acc = {0.f, 0.f, 0.f, 0.f};
#pragma unroll
            for (int k0 = 0; k0 < 512; k0 += 64) {
                bf16x8 a0 = *(const bf16x8*)(Ar + k0);
                bf16x8 a1 = *(const bf16x8*)(Ar + k0 + 32);
                bf16x8 h0v = *(const bf16x8*)(&hb[l15][k0 + lg * 8]);
                bf16x8 h1v = *(const bf16x8*)(&hb[l15][k0 + 32 + lg * 8]);
                acc = __builtin_amdgcn_mfma_f32_16x16x32_bf16(a0, h0v, acc, 0, 0, 0);
                acc = __builtin_amdgcn_mfma_f32_16x16x32_bf16(a1, h1v, acc, 0, 0, 0);
            }
            // OP2 weighted sum: 144 contiguous bf16 per lane
            const unsigned short* opb = OP2 + ((size_t)b1 * 2048 + (size_t)(m0 + 4 * lg)) * 36;
            union { ushort4 v[36]; unsigned short u[144]; } ov;
#pragma unroll
            for (int j = 0; j < 36; ++j) ov.v[j] = *(const ushort4*)(opb + j * 4);
            float og0 = 0.f, og1 = 0.f, og2 = 0.f, og3 = 0.f;
#pragma unroll
            for (int r = 0; r < RR; ++r) {
                float w = ras[l15][r];
                og0 = fmaf(w, b2f(ov.u[r]), og0);
                og1 = fmaf(w, b2f(ov.u[36 + r]), og1);
                og2 = fmaf(w, b2f(ov.u[72 + r]), og2);
                og3 = fmaf(w, b2f(ov.u[108 + r]), og3);
            }
            const float* geb = ge + ((size_t)t * B64 + b1) * 2048;
            float gi = acc[0] + og0 + geb[hpb];
            float gf = acc[1] + og1 + geb[512 + hpb];
            float gg = acc[2] + og2 + geb[1024 + hpb];
            float go = acc[3] + og3 + geb[1536 + hpb];
            float ii = 1.0f / (1.0f + expf(-gi));
            float ff = 1.0f / (1.0f + expf(-gf));
            float oo = 1.0f / (1.0f + expf(-go));
            float g2 = tanhf(gg);
            float cold = cT[hpb * 64 + b1];
            float cn = ff * cold + ii * g2;
            float hn = oo * tanhf(cn);
            bool act = dec1 > t;
            if (act) cT[hpb * 64 + b1] = cn;
            unsigned short hv = act ? f2b(hn) : hb[l15][hpb];
            int pv = __shfl_xor((int)(unsigned)hv, 16);
            if ((lg & 1) == 0) {
                unsigned u = (unsigned)hv | (((unsigned)pv & 0xFFFFu) << 16);
                __hip_atomic_store(&hdst[b1 * 256 + (hpb >> 1)], u,
                                   __ATOMIC_RELAXED, __HIP_MEMORY_SCOPE_AGENT);
            }
        }
        gbar(cnt, 2 * t + 1);

        // ================= phase 2: attention / u_t / ra (block = b2) ========
        {
            if (tid < 256) {
                unsigned u = __hip_atomic_load(&hdst[b2 * 256 + tid],
                                               __ATOMIC_RELAXED, __HIP_MEMORY_SCOPE_AGENT);
                float h0v = b2f((unsigned short)(u & 0xFFFFu));
                float h1v = b2f((unsigned short)(u >> 16));
                hs[2 * tid] = h0v; hs[2 * tid + 1] = h1v;
                red1[tid] = h0v * wh_b[2 * tid] + h1v * wh_b[2 * tid + 1];
            }
            __syncthreads();
            // u[e]: coalesced native-layout matvec, split k in 2 halves
            {
                int e = tid & 255, hf = tid >> 8;
                float u = 0.0f;
                const unsigned short* wp = whB + (size_t)(hf * 256) * 256 + e;
                const float* hq = hs + hf * 256;
#pragma unroll 8
                for (int k = 0; k < 256; ++k)
                    u = fmaf(b2f(wp[k * 256]), hq[k], u);
                up[e][hf] = u;
            }
            // rvec partials: tid < 288 -> (r, q) 64-k chunks, bf16 rh
            if (tid < RR * 8) {
                int r = tid >> 3, q = tid & 7;
                const unsigned short* rh = rh_b16 + ((size_t)(b2 * RR + r)) * 512 + q * 64;
                const float* hq = hs + q * 64;
                float a = 0.0f;
#pragma unroll
                for (int i = 0; i < 8; ++i) {
                    bf16x8 v = *(const bf16x8*)(rh + i * 8);
#pragma unroll
                    for (int j = 0; j < 8; ++j)
                        a = fmaf(b2f((unsigned short)v[j]), hq[i * 8 + j], a);
                }
                rpart[r][q] = a;
            }
            __syncthreads();
            if (tid < 256) {
                float ut = up[tid][0] + up[tid][1] + wW[tid];
                Gb[((size_t)t * B64 + b2) * EE + tid] = f2b(ut + s_wr[b2 * EE + tid]);
                red2[tid] = ut * emb_sum[tid];
            }
            if (tid < RR) {
                float a = rpart[tid][0] + rpart[tid][1] + rpart[tid][2] + rpart[tid][3]
                        + rpart[tid][4] + rpart[tid][5] + rpart[tid][6] + rpart[tid][7];
                rvec_s[tid] = a + r_lin[b2 * RR + tid];
            }
            __syncthreads();
            for (int s = 128; s > 0; s >>= 1) {
                if (tid < s) { red1[tid] += red1[tid + s]; red2[tid] += red2[tid + s]; }
                __syncthreads();
            }
            if (tid < 64) {
                float hwb = red1[0] + w_b[0];
                float wtsum = red2[0] + 12000.0f * hwb;
                float rv = (tid < RR) ? rvec_s[tid] : 0.0f;
                float lgv = (tid < RR) ? (wtsum + sumv[b2 * RR + tid] + rv) : -3.0e38f;
                float mx = lgv;
#pragma unroll
                for (int o = 32; o > 0; o >>= 1) mx = fmaxf(mx, __shfl_xor(mx, o));
                float ev = (tid < RR) ? __expf(lgv - mx) : 0.0f;
                float sm = ev, rvs = rv;
#pragma unroll
                for (int o = 32; o > 0; o >>= 1) { sm += __shfl_xor(sm, o); rvs += __shfl_xor(rvs, o); }
                if (tid < RR) ra_s[tid] = ev / sm;
                if (tid == 0) g0[t * B64 + b2] = hwb + srb[b2] + rvs;
            }
            __syncthreads();
            bool act2 = dec2 > t;
            if (tid < RR) {
                attn_out[((size_t)b2 * TDEC + t) * RR + tid] = act2 ? ra_s[tid] : 0.0f;
                if (act2)
                    __hip_atomic_store(&ra_g[b2 * RR + tid], ra_s[tid],
                                       __ATOMIC_RELAXED, __HIP_MEMORY_SCOPE_AGENT);
            }
        }
        if (t != TDEC - 1) gbar(cnt, 2 * t + 2);
    }
}

// ---------------- final predictions MFMA + LDS-staged coalesced stores ------
__global__ __launch_bounds__(256) void k_preds(
    const unsigned short* __restrict__ Gb, const unsigned short* __restrict__ embB,
    const float* __restrict__ g0, const int* __restrict__ dec_i,
    float* __restrict__ out)
{
    __shared__ float outs[64 * 132];
    __shared__ float sadd[64];
    __shared__ int sact[64];
    int tid = threadIdx.x;
    int wv = tid >> 6, lane = tid & 63;
    int l15 = lane & 15, lg = lane >> 4;
    int tq = blockIdx.x;
    int n00 = blockIdx.y * 128;
    int m0w = wv * 16;
    if (tid < 64) { sadd[tid] = g0[tq * 64 + tid]; sact[tid] = dec_i[tid] > tq; }
    bf16x8 afr[8];
    const unsigned short* Ar = Gb + (size_t)(tq * 64 + m0w + l15) * EE + lg * 8;
#pragma unroll
    for (int k = 0; k < 8; ++k) afr[k] = *(const bf16x8*)(Ar + k * 32);
    const bf16x8 zb = {0, 0, 0, 0, 0, 0, 0, 0};
#pragma unroll
    for (int nf = 0; nf < 8; ++nf) {
        int nb = n00 + nf * 16 + l15;
        bool bok = nb < VV;
        const unsigned short* Br = embB + (size_t)nb * EE + lg * 8;
        f32x4 acc = {0.f, 0.f, 0.f, 0.f};
#pragma unroll
        for (int k = 0; k < 8; ++k) {
            bf16x8 bb8 = bok ? *(const bf16x8*)(Br + k * 32) : zb;
            acc = __builtin_amdgcn_mfma_f32_16x16x32_bf16(afr[k], bb8, acc, 0, 0, 0);
        }
#pragma unroll
        for (int r = 0; r < 4; ++r)
            outs[(m0w + 4 * lg + r) * 132 + nf * 16 + l15] = acc[r];
    }
    __syncthreads();
#pragma unroll
    for (int it = 0; it < 8; ++it) {
        int row = it * 8 + (tid >> 5);
        int c = (tid & 31) * 4;
        if (n00 + c < VV) {
            float add = sadd[row];
            bool a = sact[row] != 0;
            const float* src = outs + row * 132 + c;
            float4 v;
            v.x = a ? src[0] + add : 0.0f;
            v.y = a ? src[1] + add : 0.0f;
            v.z = a ? src[2] + add : 0.0f;
            v.w = a ? src[3] + add : 0.0f;
            *(float4*)(out + ((size_t)row * TDEC + tq) * VV + n00 + c) = v;
        }
    }
}

extern "C" void kernel_launch(void* const* d_in, const int* in_sizes, int n_in,
                              void* d_out, int out_size, void* d_ws, size_t ws_size,
                              hipStream_t stream)
{
    const float* h0      = (const float*)d_in[0];
    const float* objs    = (const float*)d_in[1];
    const int*   caps    = (const int*)d_in[2];
    const int*   cap_len = (const int*)d_in[3];
    const float* embW    = (const float*)d_in[4];
    const float* whW     = (const float*)d_in[5];
    const float* wh_b    = (const float*)d_in[6];
    const float* wrW     = (const float*)d_in[7];
    const float* wr_b    = (const float*)d_in[8];
    const float* rhW     = (const float*)d_in[9];
    const float* rh_b    = (const float*)d_in[10];
    const float* wW      = (const float*)d_in[11];
    const float* w_b     = (const float*)d_in[12];
    const float* rW      = (const float*)d_in[13];
    const float* r_b     = (const float*)d_in[14];
    const float* Wih     = (const float*)d_in[15];
    const float* Whh     = (const float*)d_in[16];
    const float* bih     = (const float*)d_in[17];
    const float* bhh     = (const float*)d_in[18];

    float* out = (float*)d_out;
    float* out_pred = out;                      // 64*20*12000
    float* out_attn = out + 15360000;           // 64*20*36
    float* out_caps = out + 15406080;           // 64*20
    float* out_dec  = out + 15407360;           // 64
    float* out_sind = out + 15407424;           // 64

    float* f = (float*)d_ws;
    size_t o = 0;
    float* ge      = f + o; o += (size_t)TDEC * B64 * 2048;// 2,621,440
    float* cT      = f + o; o += (size_t)HH * B64;
    float* g0      = f + o; o += TDEC * B64;
    float* embpart = f + o; o += 240 * EE;
    float* emb_sum = f + o; o += EE;
    float* pw      = f + o; o += DD;
    float* sumv    = f + o; o += B64 * RR;
    float* r_lin   = f + o; o += B64 * RR;
    float* s_wr    = f + o; o += B64 * EE;
    float* srb     = f + o; o += B64;
    float* ra_g    = f + o; o += B64 * RR;
    o = (o + 3) & ~(size_t)3;
    unsigned short* us = (unsigned short*)(f + o);
    size_t uo = 0;
    unsigned short* objs_b = us + uo; uo += (size_t)B64 * RR * DD;   // 2,359,296
    unsigned short* AembB  = us + uo; uo += (size_t)TDEC * B64 * EE; // 327,680
    unsigned short* embB   = us + uo; uo += (size_t)VV * EE;         // 3,072,000
    unsigned short* WihB   = us + uo; uo += (size_t)2048 * EE;       // 524,288
    unsigned short* whB    = us + uo; uo += (size_t)HH * EE;         // 131,072
    unsigned short* rhW_b  = us + uo; uo += (size_t)HH * DD;         // 524,288
    unsigned short* Wc     = us + uo; uo += (size_t)2048 * 1536;     // 3,145,728
    unsigned short* Gb     = us + uo; uo += (size_t)TDEC * B64 * EE; // 327,680
    unsigned short* rh_b16 = us + uo; uo += (size_t)B64 * RR * HH;   // 1,179,648
    unsigned short* OP2    = us + uo; uo += (size_t)B64 * 2048 * RR; // 4,718,592
    uo = (uo + 1) & ~(size_t)1;
    unsigned* ub = (unsigned*)(us + uo);
    unsigned* hbuf0 = ub;            // 64*256
    unsigned* hbuf1 = ub + 16384;
    unsigned* cnt   = ub + 32768;
    int* ibase  = (int*)(ub + 32772);
    int* sind   = ibase;
    int* dec_i  = ibase + 64;
    int* caps_s = ibase + 128;

    k_sort<<<1, 64, 0, stream>>>(cap_len, caps, sind, dec_i, caps_s, out_dec, out_sind, out_caps);
    k_init<<<128, 256, 0, stream>>>(h0, sind, hbuf0, cT, ra_g, cnt);
    k_gobjs<<<9216, 256, 0, stream>>>(objs, sind, objs_b);
    k_gA<<<1280, 256, 0, stream>>>(embW, caps_s, AembB);
    k_prep<<<8192, 256, 0, stream>>>(embW, Wih, Whh, rhW, whW, embB, WihB, rhW_b, whB, Wc);
    k_embsum<<<240, 256, 0, stream>>>(embW, embpart);
    k_embred<<<1, 256, 0, stream>>>(embpart, emb_sum);
    k_pwsum<<<4, 256, 0, stream>>>(emb_sum, wrW, wr_b, pw);
    k_objpre<<<64, 256, 0, stream>>>(objs_b, wrW, wr_b, pw, rW, r_b, s_wr, srb, sumv, r_lin);
    {
        dim3 g1(72, 16);   // rh_b16: M=2304, N=512, K=1024
        k_bgemm16<<<g1, 256, 0, stream>>>(objs_b, DD, rhW_b, DD, rh_b16, HH, DD, rh_b);
        dim3 g2(40, 64);   // ge: M=1280, N=2048, K=256
        k_bgemm<<<g2, 256, 0, stream>>>(AembB, EE, WihB, EE, ge, 2048, EE, bih, bhh);
        dim3 g3(72, 64);   // OP2: M=2304, N=2048, K=1024
        k_opgemm<<<g3, 256, 0, stream>>>(objs_b, Wc, OP2);
    }
    {
        void* args[] = {
            (void*)&Wc, (void*)&OP2, (void*)&ge, (void*)&cT, (void*)&dec_i,
            (void*)&rh_b16, (void*)&sumv, (void*)&r_lin, (void*)&whB,
            (void*)&wh_b, (void*)&wW, (void*)&w_b, (void*)&emb_sum,
            (void*)&s_wr, (void*)&srb, (void*)&hbuf0, (void*)&hbuf1,
            (void*)&ra_g, (void*)&cnt, (void*)&Gb, (void*)&g0, (void*)&out_attn
        };
        hipLaunchCooperativeKernel((const void*)k_recur, dim3(64), dim3(512), args, 0, stream);
    }
    {
        dim3 g4(20, 94);
        k_preds<<<g4, 256, 0, stream>>>(Gb, embB, g0, dec_i, out_pred);
    }
}